// Round 2
// 1080.842 us; speedup vs baseline: 2.3878x; 2.3878x over previous
//
#include <hip/hip_runtime.h>
#include <hip/hip_bf16.h>
#include <cstddef>

#define T_TOK 2048
#define HID   2048
#define NE    32
#define TOPK  8
#define INTER_ 768
#define LDA 40  // LDS leading dim in shorts for 32-wide K tiles (+8 pad -> 2-way max conflict, free)

typedef __attribute__((ext_vector_type(8))) short bf16x8;
typedef __attribute__((ext_vector_type(4))) float f32x4;

__device__ inline short f2bf(float f) {
    union { float f; unsigned u; } v; v.f = f;
    unsigned r = (v.u + 0x7FFFu + ((v.u >> 16) & 1u)) >> 16;
    return (short)r;
}

// ---------------- router: fp32 logits -> softmax -> top8 -> top-p keep -> renorm ----------------
__global__ __launch_bounds__(256) void router_kernel(
    const float* __restrict__ x, const float* __restrict__ gw,
    __hip_bfloat16* __restrict__ x_bf,
    int* __restrict__ counts, int* __restrict__ tok_list, float* __restrict__ wt_list)
{
    int t = blockIdx.x;
    __shared__ float xs[HID];
    __shared__ float lg[NE];
    const float* xrow = x + (size_t)t * HID;
    for (int i = threadIdx.x; i < HID; i += 256) {
        float v = xrow[i];
        xs[i] = v;
        x_bf[(size_t)t * HID + i] = __float2bfloat16(v);
    }
    __syncthreads();
    int wave = threadIdx.x >> 6, lane = threadIdx.x & 63;
    for (int e8 = 0; e8 < 8; ++e8) {
        int e = wave * 8 + e8;
        const float* wr = gw + (size_t)e * HID;
        float s = 0.f;
        for (int k = lane; k < HID; k += 64) s += xs[k] * wr[k];
        #pragma unroll
        for (int off = 32; off > 0; off >>= 1) s += __shfl_down(s, off);
        if (lane == 0) lg[e] = s;
    }
    __syncthreads();
    if (threadIdx.x == 0) {
        float mx = lg[0];
        for (int e = 1; e < NE; ++e) mx = fmaxf(mx, lg[e]);
        float pr[NE]; float sum = 0.f;
        for (int e = 0; e < NE; ++e) { pr[e] = expf(lg[e] - mx); sum += pr[e]; }
        float inv = 1.f / sum;
        for (int e = 0; e < NE; ++e) pr[e] *= inv;
        float tv[TOPK]; int ti[TOPK];
        unsigned used = 0u;
        for (int j = 0; j < TOPK; ++j) {
            float bv = -1.f; int be = 0;
            for (int e = 0; e < NE; ++e)
                if (!((used >> e) & 1u) && pr[e] > bv) { bv = pr[e]; be = e; }
            used |= 1u << be;
            tv[j] = bv; ti[j] = be;
        }
        float s8 = 0.f;
        for (int j = 0; j < TOPK; ++j) s8 += tv[j];
        s8 = fmaxf(s8, 1e-12f);
        float c = 0.f; int cnt_lt = 0;
        for (int j = 0; j < TOPK; ++j) { c += tv[j] / s8; if (c < 0.8f) cnt_lt++; }
        int keep = min(cnt_lt + 1, TOPK);
        float sk = 0.f;
        for (int j = 0; j < keep; ++j) sk += tv[j];
        sk = fmaxf(sk, 1e-12f);
        for (int j = 0; j < keep; ++j) {
            float w = tv[j] / sk;
            int e = ti[j];
            int pos = atomicAdd(&counts[e], 1);
            tok_list[e * T_TOK + pos] = t;
            wt_list[e * T_TOK + pos] = w;
        }
    }
}

__global__ void prefix_kernel(const int* __restrict__ counts, int* __restrict__ base) {
    if (threadIdx.x == 0) {
        int s = 0;
        for (int e = 0; e < NE; ++e) { base[e] = s; s += counts[e]; }
        base[NE] = s;
    }
}

// ---------------- GEMM1: h = silu(X Wg^T) * (X Wu^T), BM=128, reg-prefetch, in-reg SwiGLU ----------
// grid (16 Mtiles, 12 Ntiles, 32 experts); flat dispatch id decoded so all Mtiles of one
// (expert,ntile) weight panel share an XCD (flat%8 invariant).
__global__ __launch_bounds__(256, 3) void gemm1_kernel(
    const __hip_bfloat16* __restrict__ x_bf,
    const float* __restrict__ gup,               // [32][1536][2048] fp32
    const int* __restrict__ counts, const int* __restrict__ base,
    const int* __restrict__ tok_list,
    __hip_bfloat16* __restrict__ h_buf)          // [total_pairs][768] bf16
{
    int flat = blockIdx.x + 16 * (blockIdx.y + 12 * blockIdx.z);
    int gq = flat >> 7, rem = flat & 127;
    int mt = rem >> 3, gr = rem & 7;
    int g = gq * 8 + gr;          // 0..383 = (expert, ntile) group
    int e = g & 31, nt = g >> 5;
    int cnt = counts[e];
    int m0 = mt << 7;
    if (m0 >= cnt) return;
    int n0 = nt << 6;             // 64 inter cols per block

    __shared__ short As[128 * LDA];
    __shared__ short Bg[64 * LDA];
    __shared__ short Bu[64 * LDA];

    int tid = threadIdx.x;
    int wave = tid >> 6, lane = tid & 63;
    int quad = lane >> 4, l16 = lane & 15;

    // staging assignment: 2 threads per row, 32-elem K step
    int a_row = tid >> 1, a_k = (tid & 1) * 16;  // shorts
    int tok_a = tok_list[e * T_TOK + min(m0 + a_row, cnt - 1)];
    const __hip_bfloat16* asrc = x_bf + (size_t)tok_a * HID + a_k;
    short* adst = &As[a_row * LDA + a_k];

    int b_row = tid >> 1, b_k = (tid & 1) * 16;  // floats; rows 0..63 = g, 64..127 = u
    int wr = (b_row < 64) ? (n0 + b_row) : (768 + n0 + (b_row - 64));
    const float* bsrc = gup + ((size_t)e * 1536 + wr) * HID + b_k;
    short* bdst = (b_row < 64) ? &Bg[b_row * LDA + b_k] : &Bu[(b_row - 64) * LDA + b_k];

    // prefetch K-step 0 into registers
    uint4 apf0 = *(const uint4*)(asrc);
    uint4 apf1 = *(const uint4*)(asrc + 8);
    float4 bpf0 = *(const float4*)(bsrc);
    float4 bpf1 = *(const float4*)(bsrc + 4);
    float4 bpf2 = *(const float4*)(bsrc + 8);
    float4 bpf3 = *(const float4*)(bsrc + 12);

    f32x4 acc[8][2] = {};

    for (int k0 = 0; k0 < HID; k0 += 32) {
        __syncthreads();
        // write prefetched regs -> LDS (fp32 -> bf16 for B)
        *(uint4*)(adst)     = apf0;
        *(uint4*)(adst + 8) = apf1;
        short tmp[16];
        tmp[0]=f2bf(bpf0.x); tmp[1]=f2bf(bpf0.y); tmp[2]=f2bf(bpf0.z); tmp[3]=f2bf(bpf0.w);
        tmp[4]=f2bf(bpf1.x); tmp[5]=f2bf(bpf1.y); tmp[6]=f2bf(bpf1.z); tmp[7]=f2bf(bpf1.w);
        tmp[8]=f2bf(bpf2.x); tmp[9]=f2bf(bpf2.y); tmp[10]=f2bf(bpf2.z); tmp[11]=f2bf(bpf2.w);
        tmp[12]=f2bf(bpf3.x); tmp[13]=f2bf(bpf3.y); tmp[14]=f2bf(bpf3.z); tmp[15]=f2bf(bpf3.w);
        *(uint4*)(bdst)     = *(uint4*)&tmp[0];
        *(uint4*)(bdst + 8) = *(uint4*)&tmp[8];
        __syncthreads();
        // issue next K-step's global loads BEFORE the MFMA phase (latency hides under it)
        int kn = k0 + 32;
        if (kn < HID) {
            apf0 = *(const uint4*)(asrc + kn);
            apf1 = *(const uint4*)(asrc + kn + 8);
            bpf0 = *(const float4*)(bsrc + kn);
            bpf1 = *(const float4*)(bsrc + kn + 4);
            bpf2 = *(const float4*)(bsrc + kn + 8);
            bpf3 = *(const float4*)(bsrc + kn + 12);
        }
        // each wave: 16 cols (both g and u), all 128 rows
        bf16x8 bg = *(const bf16x8*)&Bg[(wave * 16 + l16) * LDA + quad * 8];
        bf16x8 bu = *(const bf16x8*)&Bu[(wave * 16 + l16) * LDA + quad * 8];
        #pragma unroll
        for (int rt = 0; rt < 8; ++rt) {
            bf16x8 af = *(const bf16x8*)&As[(rt * 16 + l16) * LDA + quad * 8];
            acc[rt][0] = __builtin_amdgcn_mfma_f32_16x16x32_bf16(af, bg, acc[rt][0], 0, 0, 0);
            acc[rt][1] = __builtin_amdgcn_mfma_f32_16x16x32_bf16(af, bu, acc[rt][1], 0, 0, 0);
        }
    }

    // in-register SwiGLU epilogue (C/D layout: col = l16, row = quad*4 + i)
    int hb0 = base[e] + m0;
    int col = n0 + wave * 16 + l16;
    #pragma unroll
    for (int rt = 0; rt < 8; ++rt)
        #pragma unroll
        for (int i = 0; i < 4; ++i) {
            int row = rt * 16 + quad * 4 + i;
            if (m0 + row < cnt) {
                float gg = acc[rt][0][i], uu = acc[rt][1][i];
                float h = (gg / (1.f + expf(-gg))) * uu;
                h_buf[(size_t)(hb0 + row) * INTER_ + col] = __float2bfloat16(h);
            }
        }
}

// ---------------- GEMM2: out[tok] += w * (h Wd^T), BM=128, BN=128, reg-prefetch ----------------
__global__ __launch_bounds__(256, 3) void gemm2_kernel(
    const __hip_bfloat16* __restrict__ h_buf,
    const float* __restrict__ dproj,             // [32][2048][768] fp32
    const int* __restrict__ counts, const int* __restrict__ base,
    const int* __restrict__ tok_list, const float* __restrict__ wt_list,
    float* __restrict__ out)
{
    int flat = blockIdx.x + 16 * (blockIdx.y + 16 * blockIdx.z);
    int gq = flat >> 7, rem = flat & 127;
    int mt = rem >> 3, gr = rem & 7;
    int g = gq * 8 + gr;          // 0..511 = (expert, ntile) group
    int e = g & 31, nt = g >> 5;
    int cnt = counts[e];
    int m0 = mt << 7;
    if (m0 >= cnt) return;
    int n0 = nt << 7;             // 128 out cols per block

    __shared__ int toks[128];
    __shared__ float wts[128];
    __shared__ short As[128 * LDA];
    __shared__ short Bs[128 * LDA];

    int tid = threadIdx.x;
    if (tid < 128) {
        int r = min(m0 + tid, cnt - 1);
        toks[tid] = tok_list[e * T_TOK + r];
        wts[tid]  = wt_list[e * T_TOK + r];
    }
    int wave = tid >> 6, lane = tid & 63;
    int quad = lane >> 4, l16 = lane & 15;

    int a_row = tid >> 1, a_k = (tid & 1) * 16;  // shorts
    const __hip_bfloat16* asrc = h_buf + (size_t)(base[e] + min(m0 + a_row, cnt - 1)) * INTER_ + a_k;
    short* adst = &As[a_row * LDA + a_k];
    int b_row = tid >> 1, b_k = (tid & 1) * 16;  // floats
    const float* bsrc = dproj + (size_t)e * HID * INTER_ + (size_t)(n0 + b_row) * INTER_ + b_k;
    short* bdst = &Bs[b_row * LDA + b_k];

    uint4 apf0 = *(const uint4*)(asrc);
    uint4 apf1 = *(const uint4*)(asrc + 8);
    float4 bpf0 = *(const float4*)(bsrc);
    float4 bpf1 = *(const float4*)(bsrc + 4);
    float4 bpf2 = *(const float4*)(bsrc + 8);
    float4 bpf3 = *(const float4*)(bsrc + 12);

    f32x4 acc[8][2] = {};

    for (int k0 = 0; k0 < INTER_; k0 += 32) {
        __syncthreads();
        *(uint4*)(adst)     = apf0;
        *(uint4*)(adst + 8) = apf1;
        short tmp[16];
        tmp[0]=f2bf(bpf0.x); tmp[1]=f2bf(bpf0.y); tmp[2]=f2bf(bpf0.z); tmp[3]=f2bf(bpf0.w);
        tmp[4]=f2bf(bpf1.x); tmp[5]=f2bf(bpf1.y); tmp[6]=f2bf(bpf1.z); tmp[7]=f2bf(bpf1.w);
        tmp[8]=f2bf(bpf2.x); tmp[9]=f2bf(bpf2.y); tmp[10]=f2bf(bpf2.z); tmp[11]=f2bf(bpf2.w);
        tmp[12]=f2bf(bpf3.x); tmp[13]=f2bf(bpf3.y); tmp[14]=f2bf(bpf3.z); tmp[15]=f2bf(bpf3.w);
        *(uint4*)(bdst)     = *(uint4*)&tmp[0];
        *(uint4*)(bdst + 8) = *(uint4*)&tmp[8];
        __syncthreads();
        int kn = k0 + 32;
        if (kn < INTER_) {
            apf0 = *(const uint4*)(asrc + kn);
            apf1 = *(const uint4*)(asrc + kn + 8);
            bpf0 = *(const float4*)(bsrc + kn);
            bpf1 = *(const float4*)(bsrc + kn + 4);
            bpf2 = *(const float4*)(bsrc + kn + 8);
            bpf3 = *(const float4*)(bsrc + kn + 12);
        }
        bf16x8 b0 = *(const bf16x8*)&Bs[(wave * 32 + l16) * LDA + quad * 8];
        bf16x8 b1 = *(const bf16x8*)&Bs[(wave * 32 + 16 + l16) * LDA + quad * 8];
        #pragma unroll
        for (int rt = 0; rt < 8; ++rt) {
            bf16x8 af = *(const bf16x8*)&As[(rt * 16 + l16) * LDA + quad * 8];
            acc[rt][0] = __builtin_amdgcn_mfma_f32_16x16x32_bf16(af, b0, acc[rt][0], 0, 0, 0);
            acc[rt][1] = __builtin_amdgcn_mfma_f32_16x16x32_bf16(af, b1, acc[rt][1], 0, 0, 0);
        }
    }

    #pragma unroll
    for (int rt = 0; rt < 8; ++rt)
        #pragma unroll
        for (int ct = 0; ct < 2; ++ct)
            #pragma unroll
            for (int i = 0; i < 4; ++i) {
                int row = rt * 16 + quad * 4 + i;
                if (m0 + row < cnt) {
                    int col = n0 + wave * 32 + ct * 16 + l16;
                    float v = acc[rt][ct][i] * wts[row];
                    atomicAdd(&out[(size_t)toks[row] * HID + col], v);
                }
            }
}

extern "C" void kernel_launch(void* const* d_in, const int* in_sizes, int n_in,
                              void* d_out, int out_size, void* d_ws, size_t ws_size,
                              hipStream_t stream)
{
    const float* x   = (const float*)d_in[0];
    const float* gw  = (const float*)d_in[1];
    const float* gup = (const float*)d_in[2];
    const float* dpj = (const float*)d_in[3];
    float* out = (float*)d_out;

    char* ws = (char*)d_ws;
    size_t off = 0;
    __hip_bfloat16* x_bf = (__hip_bfloat16*)(ws + off); off += (size_t)T_TOK * HID * 2;
    int* counts = (int*)(ws + off); off += 256;
    int* base   = (int*)(ws + off); off += 256;
    int* tok_list = (int*)(ws + off); off += (size_t)NE * T_TOK * 4;
    float* wt_list = (float*)(ws + off); off += (size_t)NE * T_TOK * 4;
    __hip_bfloat16* h_buf = (__hip_bfloat16*)(ws + off); off += (size_t)T_TOK * TOPK * INTER_ * 2;

    hipMemsetAsync(counts, 0, 256, stream);
    hipMemsetAsync(d_out, 0, (size_t)out_size * sizeof(float), stream);
    router_kernel<<<T_TOK, 256, 0, stream>>>(x, gw, x_bf, counts, tok_list, wt_list);
    prefix_kernel<<<1, 64, 0, stream>>>(counts, base);
    gemm1_kernel<<<dim3(16, 12, 32), 256, 0, stream>>>(x_bf, gup, counts, base, tok_list, h_buf);
    gemm2_kernel<<<dim3(16, 16, 32), 256, 0, stream>>>(h_buf, dpj, counts, base, tok_list, wt_list, out);
}